// Round 18
// baseline (179.288 us; speedup 1.0000x reference)
//
#include <hip/hip_runtime.h>

#define DD 1024   // hidden size
#define MM 256    // random features
#define NN 16384  // hidden states
#define KK 8192   // weight rows

typedef float f32x4 __attribute__((ext_vector_type(4)));
typedef float f32x2 __attribute__((ext_vector_type(2)));
typedef unsigned int u32x4 __attribute__((ext_vector_type(4)));
typedef unsigned int u32x2 __attribute__((ext_vector_type(2)));
typedef __bf16 bf16x8 __attribute__((ext_vector_type(8)));
typedef unsigned short u16;
typedef unsigned int u32;

static __device__ __forceinline__ u16 f2bf(float f) {
    u32 u = __builtin_bit_cast(u32, f);
    u32 r = u + 0x7fffu + ((u >> 16) & 1u);
    return (u16)(r >> 16);
}
static __device__ __forceinline__ float bf2f(u16 h) {
    u32 u = ((u32)h) << 16;
    return __builtin_bit_cast(float, u);
}

static __device__ __forceinline__ void gload_lds16(const void* g, void* l) {
    __builtin_amdgcn_global_load_lds(
        (const __attribute__((address_space(1))) u32*)g,
        (__attribute__((address_space(3))) u32*)l, 16, 0, 0);
}

static __device__ __forceinline__ bf16x8 ldfrag(const u16* p) {
    return __builtin_bit_cast(bf16x8, *(const u32x4*)p);
}

#define MFMA16(a, b, c) __builtin_amdgcn_mfma_f32_16x16x32_bf16((a), (b), (c), 0, 0, 0)

// ---------------------------------------------------------------------------
// Kernel 1: omega fp32 -> (hi, lo) bf16 split   [R5 verbatim]
// ---------------------------------------------------------------------------
__global__ void k_conv(const float* __restrict__ om, u16* __restrict__ oh,
                       u16* __restrict__ ol) {
    int i = (blockIdx.x * blockDim.x + threadIdx.x) * 4;
    f32x4 x = *(const f32x4*)(om + i);
    ushort4 h, l;
    u16 t;
    t = f2bf(x.x); h.x = t; l.x = f2bf(x.x - bf2f(t));
    t = f2bf(x.y); h.y = t; l.y = f2bf(x.y - bf2f(t));
    t = f2bf(x.z); h.z = t; l.z = f2bf(x.z - bf2f(t));
    t = f2bf(x.w); h.w = t; l.w = f2bf(x.w - bf2f(t));
    *(ushort4*)(oh + i) = h;
    *(ushort4*)(ol + i) = l;
}

// ---------------------------------------------------------------------------
// Kernel 2: Stage A v4 — SAME algorithm/LDS/traffic as v3, repartitioned to
// 512 threads (8 waves) per 32-row block. Each wave owns 32 output cols
// (MT=2, NT=2, 12 MFMA/step). Grid stays 768 -> 3 blocks/CU = 24 waves/CU
// (6/SIMD, 2x the TLP of the 256-thread version) to fill the ~50% idle
// measured in R14 (MfmaUtil 25%, VALUBusy 24%). Per-thread staging halves.
// ---------------------------------------------------------------------------
__global__ __launch_bounds__(512, 6)
void k_stageA(const float* __restrict__ Hs, const float* __restrict__ Ws,
              const u16* __restrict__ Oh, const u16* __restrict__ Ol,
              u16* __restrict__ phiH, u16* __restrict__ phiW,
              float* __restrict__ emH, float* __restrict__ emW)
{
    __shared__ alignas(16) u16 Ah[32 * 32];
    __shared__ alignas(16) u16 Al[32 * 32];
    __shared__ alignas(16) u16 Bh[256 * 32];
    __shared__ alignas(16) u16 Bl[256 * 32];
    __shared__ float redmax[8][32];

    const int tid  = threadIdx.x;
    const int lane = tid & 63;
    const int wid  = tid >> 6;          // 0..7

    const float* __restrict__ X;
    u16* __restrict__ phi;
    float* __restrict__ em;
    int row0;
    if (blockIdx.x < NN / 32) {
        X = Hs; phi = phiH; em = emH; row0 = blockIdx.x * 32;
    } else {
        X = Ws; phi = phiW; em = emW; row0 = (blockIdx.x - NN / 32) * 32;
    }

    f32x4 acc[2][2];
#pragma unroll
    for (int m = 0; m < 2; ++m)
#pragma unroll
        for (int n = 0; n < 2; ++n) acc[m][n] = f32x4{0.f, 0.f, 0.f, 0.f};

    // A staging: thread loads float2 (row arow, fp32 cols acol..acol+1)
    const int arow = tid >> 4;           // 0..31
    const int acol = (tid & 15) * 2;     // 0,2,..,30
    const float* __restrict__ xrow = X + (long)(row0 + arow) * DD;
    const int a_idx = arow * 32 + (acol ^ (((arow >> 1) & 3) << 3));

    const int r16 = lane & 15;
    const int h8  = (lane >> 4) << 3;
    int aoffs[2], boffs[2];
#pragma unroll
    for (int m = 0; m < 2; ++m) {
        int row = m * 16 + r16;
        aoffs[m] = row * 32 + (h8 ^ (((row >> 1) & 3) << 3));
    }
#pragma unroll
    for (int n = 0; n < 2; ++n) {
        int row = wid * 32 + n * 16 + r16;
        boffs[n] = row * 32 + (h8 ^ (((row >> 1) & 3) << 3));
    }

    auto stageO = [&](int k0) {
#pragma unroll
        for (int s = 0; s < 2; ++s) {
            const int c    = s * 512 + tid;     // 0..1023
            const int brow = c >> 2;            // 0..255
            const int scol = k0 + (((c & 3) << 3) ^ (((brow >> 1) & 3) << 3));
            gload_lds16(Oh + brow * DD + scol, Bh + (s * 512 + wid * 64) * 8);
            gload_lds16(Ol + brow * DD + scol, Bl + (s * 512 + wid * 64) * 8);
        }
    };
    auto convwrite = [&](const f32x2& x) {
        u16 h0 = f2bf(x.x);
        u16 h1 = f2bf(x.y);
        u16 l0 = f2bf(x.x - bf2f(h0));
        u16 l1 = f2bf(x.y - bf2f(h1));
        *(u32*)(Ah + a_idx) = (u32)h0 | ((u32)h1 << 16);
        *(u32*)(Al + a_idx) = (u32)l0 | ((u32)l1 << 16);
    };

    // prologue: tile 0 fully into LDS; prefetch X(1) to regs
    stageO(0);
    f32x2 x0 = *(const f32x2*)(xrow + acol);
    convwrite(x0);
    f32x2 xN = *(const f32x2*)(xrow + 32 + acol);
    __syncthreads();

    for (int ks = 0; ks < 32; ++ks) {
        // 1) read tile-ks fragments into registers
        bf16x8 fah[2], fal[2], fbh[2], fbl[2];
#pragma unroll
        for (int m = 0; m < 2; ++m) {
            fah[m] = ldfrag(Ah + aoffs[m]);
            fal[m] = ldfrag(Al + aoffs[m]);
        }
#pragma unroll
        for (int n = 0; n < 2; ++n) {
            fbh[n] = ldfrag(Bh + boffs[n]);
            fbl[n] = ldfrag(Bl + boffs[n]);
        }
        // 2) all waves' reads complete -> single LDS buffer safe to overwrite
        __syncthreads();
        // 3) issue next tile's staging NOW (lands during MFMA phase)
        if (ks + 1 < 32) {
            stageO((ks + 1) * 32);
            convwrite(xN);
        }
        if (ks + 2 < 32)
            xN = *(const f32x2*)(xrow + (ks + 2) * 32 + acol);
        // 4) MFMA on register-resident fragments
#pragma unroll
        for (int m = 0; m < 2; ++m)
#pragma unroll
            for (int n = 0; n < 2; ++n) {
                acc[m][n] = MFMA16(fah[m], fbh[n], acc[m][n]);
                acc[m][n] = MFMA16(fah[m], fbl[n], acc[m][n]);
                acc[m][n] = MFMA16(fal[m], fbh[n], acc[m][n]);
            }
        // 5) drain: staged loads had the whole MFMA+convert phase to land
        __syncthreads();
    }

    // row max: lane-local over n, then across the 16 lanes sharing a row
#pragma unroll
    for (int m = 0; m < 2; ++m) {
#pragma unroll
        for (int i = 0; i < 4; ++i) {
            float v = fmaxf(acc[m][0][i], acc[m][1][i]);
            v = fmaxf(v, __shfl_xor(v, 1));
            v = fmaxf(v, __shfl_xor(v, 2));
            v = fmaxf(v, __shfl_xor(v, 4));
            v = fmaxf(v, __shfl_xor(v, 8));
            if (r16 == 0) redmax[wid][m * 16 + ((lane >> 4) << 2) + i] = v;
        }
    }
    __syncthreads();
    if (tid < 32) {
        float fm = redmax[0][tid];
#pragma unroll
        for (int w = 1; w < 8; ++w) fm = fmaxf(fm, redmax[w][tid]);
        // em = exp(-clamp(max)) so stage B epilogue needs no log/exp
        em[row0 + tid] = __expf(fminf(fmaxf(-fm, -87.f), 87.f));
    }
#pragma unroll
    for (int m = 0; m < 2; ++m) {
#pragma unroll
        for (int i = 0; i < 4; ++i) {
            const int rl = m * 16 + ((lane >> 4) << 2) + i;
            float fm = redmax[0][rl];
#pragma unroll
            for (int w = 1; w < 8; ++w) fm = fmaxf(fm, redmax[w][rl]);
#pragma unroll
            for (int n = 0; n < 2; ++n) {
                float p   = acc[m][n][i];
                float ph_ = (__expf(p - fm) + 1e-6f) * 0.0625f;
                phi[(long)(row0 + rl) * MM + wid * 32 + n * 16 + r16] = f2bf(ph_);
            }
        }
    }
}

// ---------------------------------------------------------------------------
// Kernel 3: Stage B — WIDE TILE 64x256 [R17 verbatim — best]
//   out = rf' / (rf' + eh*ew),  rf' = rf + 1e-10
// ---------------------------------------------------------------------------
__global__ __launch_bounds__(256, 3)
void k_stageB(const u16* __restrict__ PH, const u16* __restrict__ PW,
              const float* __restrict__ EH, const float* __restrict__ EW,
              float* __restrict__ out)
{
    // union: K-loop staging As 8KB + Bs 32KB | epilogue ftile 32x260 f32 (33.3KB)
    __shared__ alignas(16) unsigned char smem_raw[40 * 1024];
    u16* const As = (u16*)smem_raw;              // 64 rows x 64 cols
    u16* const Bs = As + 64 * 64;                // 256 rows x 64 cols
    float* const ftile = (float*)smem_raw;
    const int FST = 260;                         // 32 x 260 f32, pad 4

    const int tid  = threadIdx.x;
    const int lane = tid & 63;
    const int wid  = tid >> 6;
    const int bm   = blockIdx.x >> 5;   // 0..255
    const int bn   = blockIdx.x & 31;   // 0..31
    const int row0 = bm * 64, col0 = bn * 256;
    const int r16  = lane & 15;
    const int h8   = (lane >> 4) << 3;

    f32x4 acc[4][4];
#pragma unroll
    for (int m = 0; m < 4; ++m)
#pragma unroll
        for (int n = 0; n < 4; ++n) acc[m][n] = f32x4{0.f, 0.f, 0.f, 0.f};

    // fragment offsets (u16 units); rows 128B, byte swizzle ((row&7)<<4)
    int aoffs[2][4], boffs[2][4];
#pragma unroll
    for (int sl = 0; sl < 2; ++sl) {
#pragma unroll
        for (int m = 0; m < 4; ++m) {
            int row = m * 16 + r16;                      // A row 0..63
            aoffs[sl][m] = row * 64 + ((sl * 32 + h8) ^ ((row & 7) << 3));
        }
#pragma unroll
        for (int n = 0; n < 4; ++n) {
            int row = wid * 64 + n * 16 + r16;           // B row 0..255
            boffs[sl][n] = row * 64 + ((sl * 32 + h8) ^ ((row & 7) << 3));
        }
    }

    for (int ks = 0; ks < 4; ++ks) {
        const int k0 = ks * 64;
        // A panel: 64 rows x 64 k = 8KB -> 2 gl_lds/thread
#pragma unroll
        for (int s = 0; s < 2; ++s) {
            const int c    = s * 256 + tid;
            const int row  = c >> 3;
            const int scol = k0 + ((((c & 7) << 3)) ^ ((row & 7) << 3));
            gload_lds16(PH + (long)(row0 + row) * MM + scol, As + c * 8);
        }
        // B panel: 256 rows x 64 k = 32KB -> 8 gl_lds/thread
#pragma unroll
        for (int s = 0; s < 8; ++s) {
            const int c    = s * 256 + tid;
            const int row  = c >> 3;
            const int scol = k0 + ((((c & 7) << 3)) ^ ((row & 7) << 3));
            gload_lds16(PW + (long)(col0 + row) * MM + scol, Bs + c * 8);
        }
        __syncthreads();
#pragma unroll
        for (int sl = 0; sl < 2; ++sl) {
            bf16x8 fa[4], fb[4];
#pragma unroll
            for (int m = 0; m < 4; ++m) fa[m] = ldfrag(As + aoffs[sl][m]);
#pragma unroll
            for (int n = 0; n < 4; ++n) fb[n] = ldfrag(Bs + boffs[sl][n]);
#pragma unroll
            for (int m = 0; m < 4; ++m)
#pragma unroll
                for (int n = 0; n < 4; ++n)
                    acc[m][n] = MFMA16(fa[m], fb[n], acc[m][n]);
        }
        __syncthreads();
    }
    // K-loop's final __syncthreads drained everything: As/Bs reads retired.

    // epilogue: 2 passes of 32 rows x 256 cols through ftile; LDS-only sync.
    float ew_[4];
#pragma unroll
    for (int n = 0; n < 4; ++n) ew_[n] = EW[col0 + wid * 64 + n * 16 + r16];

#pragma unroll
    for (int mm = 0; mm < 2; ++mm) {
        if (mm == 1) {
            // WAR: pass-0 ftile ds_reads must retire before overwrite
            asm volatile("s_waitcnt lgkmcnt(0)" ::: "memory");
            __builtin_amdgcn_s_barrier();
        }
#pragma unroll
        for (int ms = 0; ms < 2; ++ms) {
            const int m = 2 * mm + ms;
#pragma unroll
            for (int i = 0; i < 4; ++i) {
                const int q    = ((lane >> 4) << 2) + i;       // 0..15
                const int lr   = ms * 16 + q;                  // 0..31 in pass
                const int grow = row0 + m * 16 + q;
                const float eh = EH[grow];
#pragma unroll
                for (int n = 0; n < 4; ++n) {
                    float rf = acc[m][n][i] + 1e-10f;
                    float t  = eh * ew_[n];
                    float o  = rf * __builtin_amdgcn_rcpf(rf + t);
                    ftile[lr * FST + wid * 64 + n * 16 + r16] = o;
                }
            }
        }
        // ds_writes visible to all waves (LDS only — no vmcnt drain)
        asm volatile("s_waitcnt lgkmcnt(0)" ::: "memory");
        __builtin_amdgcn_s_barrier();
        // readback + NT stores: one wave = one full 1KB output row
#pragma unroll
        for (int p = 0; p < 8; ++p) {
            const int r = p * 4 + wid;               // 0..31 local row
            const int c = lane * 4;                  // 0..252
            f32x4 v = *(const f32x4*)&ftile[r * FST + c];
            const int grow = row0 + mm * 32 + r;
            __builtin_nontemporal_store(
                v, (f32x4*)(out + (long)grow * KK + col0 + c));
        }
    }
}

// ---------------------------------------------------------------------------
extern "C" void kernel_launch(void* const* d_in, const int* in_sizes, int n_in,
                              void* d_out, int out_size, void* d_ws, size_t ws_size,
                              hipStream_t stream) {
    (void)in_sizes; (void)n_in; (void)out_size; (void)ws_size;
    const float* H  = (const float*)d_in[0];
    const float* W  = (const float*)d_in[1];
    const float* Om = (const float*)d_in[2];
    float* out = (float*)d_out;

    char* ws   = (char*)d_ws;
    u16*  phiH = (u16*)ws;                                       // 8 MB
    u16*  phiW = (u16*)(ws + (size_t)NN * MM * 2);               // 4 MB
    float* emh = (float*)(ws + (size_t)(NN + KK) * MM * 2);      // 64 KB
    float* emw = emh + NN;                                       // 32 KB
    u16*  oh   = (u16*)(emw + KK);                               // 512 KB
    u16*  ol   = oh + MM * DD;                                   // 512 KB

    k_conv<<<(MM * DD) / 1024, 256, 0, stream>>>(Om, oh, ol);
    k_stageA<<<(NN + KK) / 32, 512, 0, stream>>>(H, W, oh, ol, phiH, phiW, emh, emw);
    k_stageB<<<(NN / 64) * (KK / 256), 256, 0, stream>>>(phiH, phiW, emh, emw, out);
}

// Round 19
// 160.743 us; speedup vs baseline: 1.1154x; 1.1154x over previous
//
#include <hip/hip_runtime.h>

#define DD 1024   // hidden size
#define MM 256    // random features
#define NN 16384  // hidden states
#define KK 8192   // weight rows

typedef float f32x4 __attribute__((ext_vector_type(4)));
typedef unsigned int u32x4 __attribute__((ext_vector_type(4)));
typedef unsigned int u32x2 __attribute__((ext_vector_type(2)));
typedef __bf16 bf16x8 __attribute__((ext_vector_type(8)));
typedef unsigned short u16;
typedef unsigned int u32;

static __device__ __forceinline__ u16 f2bf(float f) {
    u32 u = __builtin_bit_cast(u32, f);
    u32 r = u + 0x7fffu + ((u >> 16) & 1u);
    return (u16)(r >> 16);
}
static __device__ __forceinline__ float bf2f(u16 h) {
    u32 u = ((u32)h) << 16;
    return __builtin_bit_cast(float, u);
}

static __device__ __forceinline__ void gload_lds16(const void* g, void* l) {
    __builtin_amdgcn_global_load_lds(
        (const __attribute__((address_space(1))) u32*)g,
        (__attribute__((address_space(3))) u32*)l, 16, 0, 0);
}

static __device__ __forceinline__ bf16x8 ldfrag(const u16* p) {
    return __builtin_bit_cast(bf16x8, *(const u32x4*)p);
}

#define MFMA16(a, b, c) __builtin_amdgcn_mfma_f32_16x16x32_bf16((a), (b), (c), 0, 0, 0)

// ---------------------------------------------------------------------------
// Kernel 1: omega fp32 -> (hi, lo) bf16 split   [R5 verbatim]
// ---------------------------------------------------------------------------
__global__ void k_conv(const float* __restrict__ om, u16* __restrict__ oh,
                       u16* __restrict__ ol) {
    int i = (blockIdx.x * blockDim.x + threadIdx.x) * 4;
    f32x4 x = *(const f32x4*)(om + i);
    ushort4 h, l;
    u16 t;
    t = f2bf(x.x); h.x = t; l.x = f2bf(x.x - bf2f(t));
    t = f2bf(x.y); h.y = t; l.y = f2bf(x.y - bf2f(t));
    t = f2bf(x.z); h.z = t; l.z = f2bf(x.z - bf2f(t));
    t = f2bf(x.w); h.w = t; l.w = f2bf(x.w - bf2f(t));
    *(ushort4*)(oh + i) = h;
    *(ushort4*)(ol + i) = l;
}

// ---------------------------------------------------------------------------
// Kernel 2: Stage A v5 — 64 ROWS/BLOCK, 512 threads (8 waves), R16 reorder.
// Per-wave per-step work identical to v3 (24 MFMA, 12 ds_read, 4-float
// convert): wave = 64 rows (MT=4) x 32 cols (NT=2). What changes: grid
// 768 -> 384 blocks = 2 dispatch rounds instead of 3, and Omega re-stage
// traffic halves (768 -> 384 MB of L2). Chain model: stageA ~ rounds x
// t_chain -> 2/3 of current. LDS 50.5 KB -> 2 blocks/CU (= grid's 1.5).
// ---------------------------------------------------------------------------
__global__ __launch_bounds__(512, 4)
void k_stageA(const float* __restrict__ Hs, const float* __restrict__ Ws,
              const u16* __restrict__ Oh, const u16* __restrict__ Ol,
              u16* __restrict__ phiH, u16* __restrict__ phiW,
              float* __restrict__ emH, float* __restrict__ emW)
{
    __shared__ alignas(16) u16 Ah[64 * 32];
    __shared__ alignas(16) u16 Al[64 * 32];
    __shared__ alignas(16) u16 Bh[256 * 32];
    __shared__ alignas(16) u16 Bl[256 * 32];
    __shared__ float redmax[8][64];

    const int tid  = threadIdx.x;
    const int lane = tid & 63;
    const int wid  = tid >> 6;          // 0..7

    const float* __restrict__ X;
    u16* __restrict__ phi;
    float* __restrict__ em;
    int row0;
    if (blockIdx.x < NN / 64) {
        X = Hs; phi = phiH; em = emH; row0 = blockIdx.x * 64;
    } else {
        X = Ws; phi = phiW; em = emW; row0 = (blockIdx.x - NN / 64) * 64;
    }

    f32x4 acc[4][2];
#pragma unroll
    for (int m = 0; m < 4; ++m)
#pragma unroll
        for (int n = 0; n < 2; ++n) acc[m][n] = f32x4{0.f, 0.f, 0.f, 0.f};

    // A staging: thread loads float4 (row arow 0..63, fp32 cols acol..+3)
    const int arow = tid >> 3;           // 0..63
    const int acol = (tid & 7) * 4;      // 0,4,..,28
    const float* __restrict__ xrow = X + (long)(row0 + arow) * DD;
    const int a_idx = arow * 32 + (acol ^ (((arow >> 1) & 3) << 3));

    const int r16 = lane & 15;
    const int h8  = (lane >> 4) << 3;
    int aoffs[4], boffs[2];
#pragma unroll
    for (int m = 0; m < 4; ++m) {
        int row = m * 16 + r16;          // 0..63
        aoffs[m] = row * 32 + (h8 ^ (((row >> 1) & 3) << 3));
    }
#pragma unroll
    for (int n = 0; n < 2; ++n) {
        int row = wid * 32 + n * 16 + r16;   // 0..255
        boffs[n] = row * 32 + (h8 ^ (((row >> 1) & 3) << 3));
    }

    auto stageO = [&](int k0) {
#pragma unroll
        for (int s = 0; s < 2; ++s) {
            const int c    = s * 512 + tid;     // 0..1023
            const int brow = c >> 2;            // 0..255
            const int scol = k0 + (((c & 3) << 3) ^ (((brow >> 1) & 3) << 3));
            gload_lds16(Oh + brow * DD + scol, Bh + (s * 512 + wid * 64) * 8);
            gload_lds16(Ol + brow * DD + scol, Bl + (s * 512 + wid * 64) * 8);
        }
    };
    auto convwrite = [&](const f32x4& x) {
        u32x2 ph, pl;
#pragma unroll
        for (int j = 0; j < 2; ++j) {
            u16 h0 = f2bf(x[2 * j]);
            u16 h1 = f2bf(x[2 * j + 1]);
            u16 l0 = f2bf(x[2 * j] - bf2f(h0));
            u16 l1 = f2bf(x[2 * j + 1] - bf2f(h1));
            ph[j] = (u32)h0 | ((u32)h1 << 16);
            pl[j] = (u32)l0 | ((u32)l1 << 16);
        }
        *(u32x2*)(Ah + a_idx) = ph;
        *(u32x2*)(Al + a_idx) = pl;
    };

    // prologue: tile 0 fully into LDS; prefetch X(1) to regs
    stageO(0);
    f32x4 x0 = *(const f32x4*)(xrow + acol);
    convwrite(x0);
    f32x4 xN = *(const f32x4*)(xrow + 32 + acol);
    __syncthreads();

    for (int ks = 0; ks < 32; ++ks) {
        // 1) read tile-ks fragments into registers
        bf16x8 fah[4], fal[4], fbh[2], fbl[2];
#pragma unroll
        for (int m = 0; m < 4; ++m) {
            fah[m] = ldfrag(Ah + aoffs[m]);
            fal[m] = ldfrag(Al + aoffs[m]);
        }
#pragma unroll
        for (int n = 0; n < 2; ++n) {
            fbh[n] = ldfrag(Bh + boffs[n]);
            fbl[n] = ldfrag(Bl + boffs[n]);
        }
        // 2) all waves' reads complete -> single LDS buffer safe to overwrite
        __syncthreads();
        // 3) issue next tile's staging NOW (lands during MFMA phase)
        if (ks + 1 < 32) {
            stageO((ks + 1) * 32);
            convwrite(xN);
        }
        if (ks + 2 < 32)
            xN = *(const f32x4*)(xrow + (ks + 2) * 32 + acol);
        // 4) MFMA on register-resident fragments
#pragma unroll
        for (int m = 0; m < 4; ++m)
#pragma unroll
            for (int n = 0; n < 2; ++n) {
                acc[m][n] = MFMA16(fah[m], fbh[n], acc[m][n]);
                acc[m][n] = MFMA16(fah[m], fbl[n], acc[m][n]);
                acc[m][n] = MFMA16(fal[m], fbh[n], acc[m][n]);
            }
        // 5) drain: staged loads had the whole MFMA+convert phase to land
        __syncthreads();
    }

    // row max: lane-local over n, across 16 lanes sharing a row, then waves
#pragma unroll
    for (int m = 0; m < 4; ++m) {
#pragma unroll
        for (int i = 0; i < 4; ++i) {
            float v = fmaxf(acc[m][0][i], acc[m][1][i]);
            v = fmaxf(v, __shfl_xor(v, 1));
            v = fmaxf(v, __shfl_xor(v, 2));
            v = fmaxf(v, __shfl_xor(v, 4));
            v = fmaxf(v, __shfl_xor(v, 8));
            if (r16 == 0) redmax[wid][m * 16 + ((lane >> 4) << 2) + i] = v;
        }
    }
    __syncthreads();
    if (tid < 64) {
        float fm = redmax[0][tid];
#pragma unroll
        for (int w = 1; w < 8; ++w) fm = fmaxf(fm, redmax[w][tid]);
        // em = exp(-clamp(max)) so stage B epilogue needs no log/exp
        em[row0 + tid] = __expf(fminf(fmaxf(-fm, -87.f), 87.f));
    }
#pragma unroll
    for (int m = 0; m < 4; ++m) {
#pragma unroll
        for (int i = 0; i < 4; ++i) {
            const int rl = m * 16 + ((lane >> 4) << 2) + i;
            float fm = redmax[0][rl];
#pragma unroll
            for (int w = 1; w < 8; ++w) fm = fmaxf(fm, redmax[w][rl]);
#pragma unroll
            for (int n = 0; n < 2; ++n) {
                float p   = acc[m][n][i];
                float ph_ = (__expf(p - fm) + 1e-6f) * 0.0625f;
                phi[(long)(row0 + rl) * MM + wid * 32 + n * 16 + r16] = f2bf(ph_);
            }
        }
    }
}

// ---------------------------------------------------------------------------
// Kernel 3: Stage B — WIDE TILE 64x256 [R17 verbatim — best]
//   out = rf' / (rf' + eh*ew),  rf' = rf + 1e-10
// ---------------------------------------------------------------------------
__global__ __launch_bounds__(256, 3)
void k_stageB(const u16* __restrict__ PH, const u16* __restrict__ PW,
              const float* __restrict__ EH, const float* __restrict__ EW,
              float* __restrict__ out)
{
    // union: K-loop staging As 8KB + Bs 32KB | epilogue ftile 32x260 f32 (33.3KB)
    __shared__ alignas(16) unsigned char smem_raw[40 * 1024];
    u16* const As = (u16*)smem_raw;              // 64 rows x 64 cols
    u16* const Bs = As + 64 * 64;                // 256 rows x 64 cols
    float* const ftile = (float*)smem_raw;
    const int FST = 260;                         // 32 x 260 f32, pad 4

    const int tid  = threadIdx.x;
    const int lane = tid & 63;
    const int wid  = tid >> 6;
    const int bm   = blockIdx.x >> 5;   // 0..255
    const int bn   = blockIdx.x & 31;   // 0..31
    const int row0 = bm * 64, col0 = bn * 256;
    const int r16  = lane & 15;
    const int h8   = (lane >> 4) << 3;

    f32x4 acc[4][4];
#pragma unroll
    for (int m = 0; m < 4; ++m)
#pragma unroll
        for (int n = 0; n < 4; ++n) acc[m][n] = f32x4{0.f, 0.f, 0.f, 0.f};

    // fragment offsets (u16 units); rows 128B, byte swizzle ((row&7)<<4)
    int aoffs[2][4], boffs[2][4];
#pragma unroll
    for (int sl = 0; sl < 2; ++sl) {
#pragma unroll
        for (int m = 0; m < 4; ++m) {
            int row = m * 16 + r16;                      // A row 0..63
            aoffs[sl][m] = row * 64 + ((sl * 32 + h8) ^ ((row & 7) << 3));
        }
#pragma unroll
        for (int n = 0; n < 4; ++n) {
            int row = wid * 64 + n * 16 + r16;           // B row 0..255
            boffs[sl][n] = row * 64 + ((sl * 32 + h8) ^ ((row & 7) << 3));
        }
    }

    for (int ks = 0; ks < 4; ++ks) {
        const int k0 = ks * 64;
        // A panel: 64 rows x 64 k = 8KB -> 2 gl_lds/thread
#pragma unroll
        for (int s = 0; s < 2; ++s) {
            const int c    = s * 256 + tid;
            const int row  = c >> 3;
            const int scol = k0 + ((((c & 7) << 3)) ^ ((row & 7) << 3));
            gload_lds16(PH + (long)(row0 + row) * MM + scol, As + c * 8);
        }
        // B panel: 256 rows x 64 k = 32KB -> 8 gl_lds/thread
#pragma unroll
        for (int s = 0; s < 8; ++s) {
            const int c    = s * 256 + tid;
            const int row  = c >> 3;
            const int scol = k0 + ((((c & 7) << 3)) ^ ((row & 7) << 3));
            gload_lds16(PW + (long)(col0 + row) * MM + scol, Bs + c * 8);
        }
        __syncthreads();
#pragma unroll
        for (int sl = 0; sl < 2; ++sl) {
            bf16x8 fa[4], fb[4];
#pragma unroll
            for (int m = 0; m < 4; ++m) fa[m] = ldfrag(As + aoffs[sl][m]);
#pragma unroll
            for (int n = 0; n < 4; ++n) fb[n] = ldfrag(Bs + boffs[sl][n]);
#pragma unroll
            for (int m = 0; m < 4; ++m)
#pragma unroll
                for (int n = 0; n < 4; ++n)
                    acc[m][n] = MFMA16(fa[m], fb[n], acc[m][n]);
        }
        __syncthreads();
    }
    // K-loop's final __syncthreads drained everything: As/Bs reads retired.

    // epilogue: 2 passes of 32 rows x 256 cols through ftile; LDS-only sync.
    float ew_[4];
#pragma unroll
    for (int n = 0; n < 4; ++n) ew_[n] = EW[col0 + wid * 64 + n * 16 + r16];

#pragma unroll
    for (int mm = 0; mm < 2; ++mm) {
        if (mm == 1) {
            // WAR: pass-0 ftile ds_reads must retire before overwrite
            asm volatile("s_waitcnt lgkmcnt(0)" ::: "memory");
            __builtin_amdgcn_s_barrier();
        }
#pragma unroll
        for (int ms = 0; ms < 2; ++ms) {
            const int m = 2 * mm + ms;
#pragma unroll
            for (int i = 0; i < 4; ++i) {
                const int q    = ((lane >> 4) << 2) + i;       // 0..15
                const int lr   = ms * 16 + q;                  // 0..31 in pass
                const int grow = row0 + m * 16 + q;
                const float eh = EH[grow];
#pragma unroll
                for (int n = 0; n < 4; ++n) {
                    float rf = acc[m][n][i] + 1e-10f;
                    float t  = eh * ew_[n];
                    float o  = rf * __builtin_amdgcn_rcpf(rf + t);
                    ftile[lr * FST + wid * 64 + n * 16 + r16] = o;
                }
            }
        }
        // ds_writes visible to all waves (LDS only — no vmcnt drain)
        asm volatile("s_waitcnt lgkmcnt(0)" ::: "memory");
        __builtin_amdgcn_s_barrier();
        // readback + NT stores: one wave = one full 1KB output row
#pragma unroll
        for (int p = 0; p < 8; ++p) {
            const int r = p * 4 + wid;               // 0..31 local row
            const int c = lane * 4;                  // 0..252
            f32x4 v = *(const f32x4*)&ftile[r * FST + c];
            const int grow = row0 + mm * 32 + r;
            __builtin_nontemporal_store(
                v, (f32x4*)(out + (long)grow * KK + col0 + c));
        }
    }
}

// ---------------------------------------------------------------------------
extern "C" void kernel_launch(void* const* d_in, const int* in_sizes, int n_in,
                              void* d_out, int out_size, void* d_ws, size_t ws_size,
                              hipStream_t stream) {
    (void)in_sizes; (void)n_in; (void)out_size; (void)ws_size;
    const float* H  = (const float*)d_in[0];
    const float* W  = (const float*)d_in[1];
    const float* Om = (const float*)d_in[2];
    float* out = (float*)d_out;

    char* ws   = (char*)d_ws;
    u16*  phiH = (u16*)ws;                                       // 8 MB
    u16*  phiW = (u16*)(ws + (size_t)NN * MM * 2);               // 4 MB
    float* emh = (float*)(ws + (size_t)(NN + KK) * MM * 2);      // 64 KB
    float* emw = emh + NN;                                       // 32 KB
    u16*  oh   = (u16*)(emw + KK);                               // 512 KB
    u16*  ol   = oh + MM * DD;                                   // 512 KB

    k_conv<<<(MM * DD) / 1024, 256, 0, stream>>>(Om, oh, ol);
    k_stageA<<<NN / 64 + KK / 64, 512, 0, stream>>>(H, W, oh, ol, phiH, phiW, emh, emw);
    k_stageB<<<(NN / 64) * (KK / 256), 256, 0, stream>>>(phiH, phiW, emh, emw, out);
}